// Round 8
// baseline (14434.109 us; speedup 1.0000x reference)
//
#include <hip/hip_runtime.h>
#include <math.h>

// Persistent-kernel LSTM: H=2048, SEQ=4096, fp32 (no fp32 MFMA -> vector ALU).
// 256 WGs x 512 thr, 1 WG/CU. Wave w of WG g owns hidden unit k=g*8+w; each
// lane holds 4 gate-rows x 32 cols of W_hh (128 floats).
//
// Cross-step exchange v10 = v8 (PACKED STAMPED INBOX, proven 8.39 ms) with
// DIRECT PER-WAVE PUBLISH (B2 + hpk LDS round trip removed).
//   inbox[2][2048] u64 (32 KB, LLC-resident). Word = {stamp:hi32, h:f32}.
//   Publish: each wave's lane 0 stores its own stamped word the moment its
//   gates finish. A WG's 8 stores hit the SAME 64B line within ~100cy and
//   merge in L2 (intra-line partial stores, NOT v7's scattered-line pattern
//   that caused 2.1 GB write-back). Per-word stamps tolerate half-updated
//   lines: consumers selectively reload only missing words (v8 poll,
//   byte-identical -- v9's pipelined always-reload poll REGRESSED 44% by
//   over-issuing reads to the hot lines; poll rate must stay low).
//   Removes B2 (~150cy) + LDS hpk round trip from the serial chain and
//   makes each unit visible earlier (no wait for the WG's slowest wave).
//   Slot-parity overwrite safety: publish follows B1 in program order, so
//   poll-pass at step t proves every WG finished its step-(t-1) read of the
//   slot we overwrite at step t (same induction as v8, round-4 header).
// Compute path identical to v5/v8 (fast gates, 16-shuffle reduction).
// d_ws: 32 KB.

#define HDIM 2048
#define SEQ 4096
#define NWG 256
#define TPB 512
#define GUARD_MAX 16384   // bounded retries: protocol failure -> loud wrong answer, no hang

typedef unsigned long long u64;

__device__ __forceinline__ float sigmoidf_(float x) {
  return __builtin_amdgcn_rcpf(1.0f + __expf(-x));
}
__device__ __forceinline__ float tanh_(float x) {
  float e = __expf(-2.0f * fabsf(x));
  float r = (1.0f - e) * __builtin_amdgcn_rcpf(1.0f + e);
  return copysignf(r, x);
}

// zero both slots: slot1 {stamp 0, h=0} is exactly what t=0 wants (h_{-1}=0);
// slot0 zeros mismatch wanted stamps (>=1) -> retried until written.
__global__ void lstm_init(u64* inbox) {
  const int i = blockIdx.x * 256 + threadIdx.x;   // 16 x 256 = 4096 words
  inbox[i] = 0ull;
}

__global__ __launch_bounds__(TPB, 2) void lstm_persist(
    const float* __restrict__ x, const float* __restrict__ w_ih,
    const float* __restrict__ w_hh, const float* __restrict__ b_ih,
    const float* __restrict__ b_hh, const float* __restrict__ w_out,
    const float* __restrict__ b_out, float* __restrict__ out,
    u64* __restrict__ inbox)
{
  const int wg   = blockIdx.x;
  const int tid  = threadIdx.x;
  const int wave = tid >> 6;
  const int lane = tid & 63;
  const int k    = wg * 8 + wave;   // this wave's hidden unit

  __shared__ float xs[SEQ];        // 16 KB
  __shared__ float hs[2][HDIM];    // 16 KB, double-buffered by parity
  __shared__ float wys[2][8];      // per-wave y partials, double-buffered

  // ---- one-time: weights into registers ----
  // rows g=0..3 (gates i,f,g,o of unit k): row = k + g*HDIM
  // cols per lane: {256*j + 4*lane + q}, j=0..7, q=0..3  -> 32 float4
  float4 W[32];
  float wx[4], bb[4];
  #pragma unroll
  for (int g = 0; g < 4; ++g) {
    const int row = k + g * HDIM;
    const float* rp = w_hh + (size_t)row * HDIM + lane * 4;
    #pragma unroll
    for (int j = 0; j < 8; ++j)
      W[g * 8 + j] = *(const float4*)(rp + j * 256);
    wx[g] = w_ih[row];
    bb[g] = b_ih[row] + b_hh[row];
  }
  float wo[4];
  #pragma unroll
  for (int q = 0; q < 4; ++q) wo[q] = w_out[tid + TPB * q];
  const float bout = b_out[0];

  for (int i = tid; i < SEQ; i += TPB) xs[i] = x[i];

  float cc = 0.f, hh = 0.f;
  float hv[4];
  __syncthreads();   // xs ready

  for (int t = 0; t < SEQ; ++t) {
    const int par = t & 1;

    // ---- poll+gather h_{t-1}: slot (t+1)&1, wanted stamp == t ----
    // v8 poll, byte-identical: serial loop, selective reload of missing
    // words only (keeps read pressure on hot lines low).
    {
      const u64* src = inbox + (size_t)((t + 1) & 1) * HDIM;
      const unsigned wanted = (unsigned)t;
      u64 v[4];
      #pragma unroll
      for (int q = 0; q < 4; ++q)
        v[q] = __hip_atomic_load(&src[tid + TPB * q], __ATOMIC_RELAXED,
                                 __HIP_MEMORY_SCOPE_AGENT);
      for (int guard = 0;;) {
        const int miss = ((unsigned)(v[0] >> 32) != wanted) |
                         ((unsigned)(v[1] >> 32) != wanted) |
                         ((unsigned)(v[2] >> 32) != wanted) |
                         ((unsigned)(v[3] >> 32) != wanted);
        if (!__any(miss) || ++guard > GUARD_MAX) break;
        #pragma unroll
        for (int q = 0; q < 4; ++q)      // re-load only still-missing words
          if ((unsigned)(v[q] >> 32) != wanted)
            v[q] = __hip_atomic_load(&src[tid + TPB * q], __ATOMIC_RELAXED,
                                     __HIP_MEMORY_SCOPE_AGENT);
      }
      #pragma unroll
      for (int q = 0; q < 4; ++q) {
        hv[q] = __uint_as_float((unsigned)v[q]);
        hs[par][tid + TPB * q] = hv[q];
      }
    }
    __syncthreads();  // B1: hs[par] ready

    // ---- off-path: drain y_{t-2} (wys[par^1] written at step t-1) ----
    if (t >= 2 && wg == 0 && tid == 0)
      out[t - 2] = wys[par ^ 1][0] + wys[par ^ 1][1] + wys[par ^ 1][2] +
                   wys[par ^ 1][3] + wys[par ^ 1][4] + wys[par ^ 1][5] +
                   wys[par ^ 1][6] + wys[par ^ 1][7] + bout;

    // ---- z = W_hh @ h (per-lane partials over 32 columns) ----
    float acc[4] = {0.f, 0.f, 0.f, 0.f};
    #pragma unroll
    for (int j = 0; j < 8; ++j) {
      const float4 h4 = *(const float4*)&hs[par][j * 256 + lane * 4];
      #pragma unroll
      for (int g = 0; g < 4; ++g) {
        const float4 w = W[g * 8 + j];
        acc[g] = fmaf(w.x, h4.x, acc[g]);
        acc[g] = fmaf(w.y, h4.y, acc[g]);
        acc[g] = fmaf(w.z, h4.z, acc[g]);
        acc[g] = fmaf(w.w, h4.w, acc[g]);
      }
    }
    // ---- 16-shuffle reduction (verified prior rounds) ----
    const float a0 = acc[0] + __shfl_xor(acc[0], 32, 64);
    const float a1 = acc[1] + __shfl_xor(acc[1], 32, 64);
    const float a2 = acc[2] + __shfl_xor(acc[2], 32, 64);
    const float a3 = acc[3] + __shfl_xor(acc[3], 32, 64);
    const bool lohalf = (lane < 32);
    float s01 = lohalf ? a0 : a1;
    float s23 = lohalf ? a2 : a3;
    #pragma unroll
    for (int off = 16; off >= 1; off >>= 1) {
      s01 += __shfl_xor(s01, off, 64);
      s23 += __shfl_xor(s23, off, 64);
    }
    const float o01 = __shfl_xor(s01, 32, 64);
    const float o23 = __shfl_xor(s23, 32, 64);
    float z[4];
    z[0] = lohalf ? s01 : o01;
    z[1] = lohalf ? o01 : s01;
    z[2] = lohalf ? s23 : o23;
    z[3] = lohalf ? o23 : s23;

    const float xt = xs[t];
    #pragma unroll
    for (int g = 0; g < 4; ++g) z[g] = fmaf(xt, wx[g], z[g] + bb[g]);

    // ---- gates (lane-redundant, identical values) ----
    const float gi = sigmoidf_(z[0]), gf = sigmoidf_(z[1]);
    const float gg = tanh_(z[2]), go = sigmoidf_(z[3]);
    cc = gf * cc + gi * gg;
    hh = go * tanh_(cc);

    // ---- publish h_t DIRECTLY: this wave's stamped word, ASAP ----
    // 8 waves of this WG hit the same 64B line -> merge in L2.
    if (lane == 0)
      __hip_atomic_store(&inbox[(size_t)(t & 1) * HDIM + k],
                         ((u64)(unsigned)(t + 1) << 32) |
                             (u64)__float_as_uint(hh),
                         __ATOMIC_RELAXED, __HIP_MEMORY_SCOPE_AGENT);

    // ---- off-path: y_{t-1} partial from hv (h_{t-1}) ----
    float sy = 0.f;
    #pragma unroll
    for (int q = 0; q < 4; ++q) sy = fmaf(wo[q], hv[q], sy);
    #pragma unroll
    for (int off = 32; off >= 1; off >>= 1) sy += __shfl_xor(sy, off, 64);
    if (lane == 0) wys[par][wave] = sy;
  }

  // ---- epilogue ----
  __syncthreads();  // wys[1] (y partial for h_{SEQ-2}) complete
  if (wg == 0 && tid == 0)
    out[SEQ - 2] = wys[1][0] + wys[1][1] + wys[1][2] + wys[1][3] + wys[1][4] +
                   wys[1][5] + wys[1][6] + wys[1][7] + bout;

  // final h, c
  if (lane == 0) {
    out[SEQ + k] = hh;
    out[SEQ + HDIM + k] = cc;
  }

  if (wg == 0) {
    // y_{SEQ-1}: poll slot (SEQ-1)&1 == 1 for stamp SEQ
    const u64* src = inbox + (size_t)1 * HDIM;
    u64 v[4];
    #pragma unroll
    for (int q = 0; q < 4; ++q)
      v[q] = __hip_atomic_load(&src[tid + TPB * q], __ATOMIC_RELAXED,
                               __HIP_MEMORY_SCOPE_AGENT);
    for (int guard = 0;;) {
      const int miss = ((unsigned)(v[0] >> 32) != (unsigned)SEQ) |
                       ((unsigned)(v[1] >> 32) != (unsigned)SEQ) |
                       ((unsigned)(v[2] >> 32) != (unsigned)SEQ) |
                       ((unsigned)(v[3] >> 32) != (unsigned)SEQ);
      if (!__any(miss) || ++guard > GUARD_MAX) break;
      #pragma unroll
      for (int q = 0; q < 4; ++q)
        if ((unsigned)(v[q] >> 32) != (unsigned)SEQ)
          v[q] = __hip_atomic_load(&src[tid + TPB * q], __ATOMIC_RELAXED,
                                   __HIP_MEMORY_SCOPE_AGENT);
    }
    float sy = 0.f;
    #pragma unroll
    for (int q = 0; q < 4; ++q)
      sy = fmaf(wo[q], __uint_as_float((unsigned)v[q]), sy);
    #pragma unroll
    for (int off = 32; off >= 1; off >>= 1) sy += __shfl_xor(sy, off, 64);
    if (lane == 0) wys[0][wave] = sy;
    __syncthreads();
    if (tid == 0)
      out[SEQ - 1] = wys[0][0] + wys[0][1] + wys[0][2] + wys[0][3] +
                     wys[0][4] + wys[0][5] + wys[0][6] + wys[0][7] + bout;
  }
}

extern "C" void kernel_launch(void* const* d_in, const int* in_sizes, int n_in,
                              void* d_out, int out_size, void* d_ws, size_t ws_size,
                              hipStream_t stream) {
  const float* x     = (const float*)d_in[0];
  const float* w_ih  = (const float*)d_in[1];
  const float* w_hh  = (const float*)d_in[2];
  const float* b_ih  = (const float*)d_in[3];
  const float* b_hh  = (const float*)d_in[4];
  const float* w_out = (const float*)d_in[5];
  const float* b_out = (const float*)d_in[6];
  float* out = (float*)d_out;

  // ws layout: inbox[2][2048] u64 = 32 KB
  u64* inbox = (u64*)d_ws;

  lstm_init<<<16, 256, 0, stream>>>(inbox);
  lstm_persist<<<NWG, TPB, 0, stream>>>(x, w_ih, w_hh, b_ih, b_hh, w_out,
                                        b_out, out, inbox);
}

// Round 9
// 8376.711 us; speedup vs baseline: 1.7231x; 1.7231x over previous
//
#include <hip/hip_runtime.h>
#include <math.h>

// Persistent-kernel LSTM: H=2048, SEQ=4096, fp32 (no fp32 MFMA -> vector ALU).
// 256 WGs x 512 thr, 1 WG/CU. Wave w of WG g owns hidden unit k=g*8+w; each
// lane holds 4 gate-rows x 32 cols of W_hh (128 floats).
//
// Cross-step exchange v8 RESTORED (champion, 8.39 ms). Final protocol law,
// triple-confirmed by v7/v10 (write side) and v9 (read side):
//   * a polled line must be produced by EXACTLY ONE wave as a SINGLE
//     full-line store (v7 scattered-lines: 2.1GB WRITE, 13.8ms; v10
//     per-wave same-line: 4x write amplification, 14.4ms);
//   * polls must be serial with SELECTIVE reload of missing words only
//     (v9 pipelined always-reload poll: +40% FETCH, 12.1ms).
//   inbox[2][2048] u64 (32 KB, LLC-resident). Word = {stamp:hi32, h:f32}.
//   A WG's 8 units = exactly one 64B line. Waves drop {t+1,h} into LDS;
//   cheap barrier B2; wave 0 lanes 0..7 emit ONE coalesced 64B line store.
//   Consumers poll their own 4 stamped words until stamp==t: the poll IS
//   the data load (no flag store, no flag-visibility trip, no drain
//   barrier, no post-detect read). One exchange barrier per step.
//   Slot-parity overwrite safety (2 slots, monotone stamps): poll-pass at
//   step s+2 proves every WG finished its step-(s+1) read of slot s&1, so
//   the step-(s+2) publish into slot s&1 cannot race a reader. hpk single-
//   buffer: wave0's publish-read at step t precedes B1(t+1) which precedes
//   any hpk write at t+1.
// Step budget (measured 2.05us): visibility ~500cy + detect ~2 sweeps
// ~1000cy + B1 + compute ~950cy + max-over-256-WG dispersion. Both
// dispersion attacks (finer poll v9, earlier publish v10) regressed;
// this is the measured floor of the protocol family.
// Compute path: v5 trims (fast gates, 16-shuffle reduction).
// d_ws: 32 KB.

#define HDIM 2048
#define SEQ 4096
#define NWG 256
#define TPB 512
#define GUARD_MAX 16384   // bounded retries: protocol failure -> loud wrong answer, no hang

typedef unsigned long long u64;

__device__ __forceinline__ float sigmoidf_(float x) {
  return __builtin_amdgcn_rcpf(1.0f + __expf(-x));
}
__device__ __forceinline__ float tanh_(float x) {
  float e = __expf(-2.0f * fabsf(x));
  float r = (1.0f - e) * __builtin_amdgcn_rcpf(1.0f + e);
  return copysignf(r, x);
}

// zero both slots: slot1 {stamp 0, h=0} is exactly what t=0 wants (h_{-1}=0);
// slot0 zeros mismatch wanted stamps (>=1) -> retried until written.
__global__ void lstm_init(u64* inbox) {
  const int i = blockIdx.x * 256 + threadIdx.x;   // 16 x 256 = 4096 words
  inbox[i] = 0ull;
}

__global__ __launch_bounds__(TPB, 2) void lstm_persist(
    const float* __restrict__ x, const float* __restrict__ w_ih,
    const float* __restrict__ w_hh, const float* __restrict__ b_ih,
    const float* __restrict__ b_hh, const float* __restrict__ w_out,
    const float* __restrict__ b_out, float* __restrict__ out,
    u64* __restrict__ inbox)
{
  const int wg   = blockIdx.x;
  const int tid  = threadIdx.x;
  const int wave = tid >> 6;
  const int lane = tid & 63;
  const int k    = wg * 8 + wave;   // this wave's hidden unit

  __shared__ float xs[SEQ];        // 16 KB
  __shared__ float hs[2][HDIM];    // 16 KB, double-buffered by parity
  __shared__ float wys[2][8];      // per-wave y partials, double-buffered
  __shared__ u64   hpk[8];         // packed {stamp,h} per wave (see header)

  // ---- one-time: weights into registers ----
  // rows g=0..3 (gates i,f,g,o of unit k): row = k + g*HDIM
  // cols per lane: {256*j + 4*lane + q}, j=0..7, q=0..3  -> 32 float4
  float4 W[32];
  float wx[4], bb[4];
  #pragma unroll
  for (int g = 0; g < 4; ++g) {
    const int row = k + g * HDIM;
    const float* rp = w_hh + (size_t)row * HDIM + lane * 4;
    #pragma unroll
    for (int j = 0; j < 8; ++j)
      W[g * 8 + j] = *(const float4*)(rp + j * 256);
    wx[g] = w_ih[row];
    bb[g] = b_ih[row] + b_hh[row];
  }
  float wo[4];
  #pragma unroll
  for (int q = 0; q < 4; ++q) wo[q] = w_out[tid + TPB * q];
  const float bout = b_out[0];

  for (int i = tid; i < SEQ; i += TPB) xs[i] = x[i];

  float cc = 0.f, hh = 0.f;
  float hv[4];
  __syncthreads();   // xs ready

  for (int t = 0; t < SEQ; ++t) {
    const int par = t & 1;

    // ---- poll+gather h_{t-1}: slot (t+1)&1, wanted stamp == t ----
    // Every thread polls its own 4 words (wave-coalesced); serial loop,
    // selective reload of missing words only.
    {
      const u64* src = inbox + (size_t)((t + 1) & 1) * HDIM;
      const unsigned wanted = (unsigned)t;
      u64 v[4];
      #pragma unroll
      for (int q = 0; q < 4; ++q)
        v[q] = __hip_atomic_load(&src[tid + TPB * q], __ATOMIC_RELAXED,
                                 __HIP_MEMORY_SCOPE_AGENT);
      for (int guard = 0;;) {
        const int miss = ((unsigned)(v[0] >> 32) != wanted) |
                         ((unsigned)(v[1] >> 32) != wanted) |
                         ((unsigned)(v[2] >> 32) != wanted) |
                         ((unsigned)(v[3] >> 32) != wanted);
        if (!__any(miss) || ++guard > GUARD_MAX) break;
        #pragma unroll
        for (int q = 0; q < 4; ++q)      // re-load only still-missing words
          if ((unsigned)(v[q] >> 32) != wanted)
            v[q] = __hip_atomic_load(&src[tid + TPB * q], __ATOMIC_RELAXED,
                                     __HIP_MEMORY_SCOPE_AGENT);
      }
      #pragma unroll
      for (int q = 0; q < 4; ++q) {
        hv[q] = __uint_as_float((unsigned)v[q]);
        hs[par][tid + TPB * q] = hv[q];
      }
    }
    __syncthreads();  // B1: hs[par] ready

    // ---- off-path: drain y_{t-2} (wys[par^1] written at step t-1) ----
    if (t >= 2 && wg == 0 && tid == 0)
      out[t - 2] = wys[par ^ 1][0] + wys[par ^ 1][1] + wys[par ^ 1][2] +
                   wys[par ^ 1][3] + wys[par ^ 1][4] + wys[par ^ 1][5] +
                   wys[par ^ 1][6] + wys[par ^ 1][7] + bout;

    // ---- z = W_hh @ h (per-lane partials over 32 columns) ----
    float acc[4] = {0.f, 0.f, 0.f, 0.f};
    #pragma unroll
    for (int j = 0; j < 8; ++j) {
      const float4 h4 = *(const float4*)&hs[par][j * 256 + lane * 4];
      #pragma unroll
      for (int g = 0; g < 4; ++g) {
        const float4 w = W[g * 8 + j];
        acc[g] = fmaf(w.x, h4.x, acc[g]);
        acc[g] = fmaf(w.y, h4.y, acc[g]);
        acc[g] = fmaf(w.z, h4.z, acc[g]);
        acc[g] = fmaf(w.w, h4.w, acc[g]);
      }
    }
    // ---- 16-shuffle reduction (verified prior rounds) ----
    const float a0 = acc[0] + __shfl_xor(acc[0], 32, 64);
    const float a1 = acc[1] + __shfl_xor(acc[1], 32, 64);
    const float a2 = acc[2] + __shfl_xor(acc[2], 32, 64);
    const float a3 = acc[3] + __shfl_xor(acc[3], 32, 64);
    const bool lohalf = (lane < 32);
    float s01 = lohalf ? a0 : a1;
    float s23 = lohalf ? a2 : a3;
    #pragma unroll
    for (int off = 16; off >= 1; off >>= 1) {
      s01 += __shfl_xor(s01, off, 64);
      s23 += __shfl_xor(s23, off, 64);
    }
    const float o01 = __shfl_xor(s01, 32, 64);
    const float o23 = __shfl_xor(s23, 32, 64);
    float z[4];
    z[0] = lohalf ? s01 : o01;
    z[1] = lohalf ? o01 : s01;
    z[2] = lohalf ? s23 : o23;
    z[3] = lohalf ? o23 : s23;

    const float xt = xs[t];
    #pragma unroll
    for (int g = 0; g < 4; ++g) z[g] = fmaf(xt, wx[g], z[g] + bb[g]);

    // ---- gates (lane-redundant, identical values) ----
    const float gi = sigmoidf_(z[0]), gf = sigmoidf_(z[1]);
    const float gg = tanh_(z[2]), go = sigmoidf_(z[3]);
    cc = gf * cc + gi * gg;
    hh = go * tanh_(cc);

    // ---- pack {stamp t+1, h_t} into LDS ----
    if (lane == 0)
      hpk[wave] = ((u64)(unsigned)(t + 1) << 32) | (u64)__float_as_uint(hh);
    __syncthreads();  // B2: hpk complete

    // ---- publish: wave 0 lanes 0..7 emit ONE 64B full-line store ----
    if (wave == 0 && lane < 8)
      __hip_atomic_store(&inbox[(size_t)(t & 1) * HDIM + wg * 8 + lane],
                         hpk[lane], __ATOMIC_RELAXED,
                         __HIP_MEMORY_SCOPE_AGENT);

    // ---- off-path: y_{t-1} partial from hv (h_{t-1}) ----
    float sy = 0.f;
    #pragma unroll
    for (int q = 0; q < 4; ++q) sy = fmaf(wo[q], hv[q], sy);
    #pragma unroll
    for (int off = 32; off >= 1; off >>= 1) sy += __shfl_xor(sy, off, 64);
    if (lane == 0) wys[par][wave] = sy;
  }

  // ---- epilogue ----
  __syncthreads();  // wys[1] (y partial for h_{SEQ-2}) complete
  if (wg == 0 && tid == 0)
    out[SEQ - 2] = wys[1][0] + wys[1][1] + wys[1][2] + wys[1][3] + wys[1][4] +
                   wys[1][5] + wys[1][6] + wys[1][7] + bout;

  // final h, c
  if (lane == 0) {
    out[SEQ + k] = hh;
    out[SEQ + HDIM + k] = cc;
  }

  if (wg == 0) {
    // y_{SEQ-1}: poll slot (SEQ-1)&1 == 1 for stamp SEQ
    const u64* src = inbox + (size_t)1 * HDIM;
    u64 v[4];
    #pragma unroll
    for (int q = 0; q < 4; ++q)
      v[q] = __hip_atomic_load(&src[tid + TPB * q], __ATOMIC_RELAXED,
                               __HIP_MEMORY_SCOPE_AGENT);
    for (int guard = 0;;) {
      const int miss = ((unsigned)(v[0] >> 32) != (unsigned)SEQ) |
                       ((unsigned)(v[1] >> 32) != (unsigned)SEQ) |
                       ((unsigned)(v[2] >> 32) != (unsigned)SEQ) |
                       ((unsigned)(v[3] >> 32) != (unsigned)SEQ);
      if (!__any(miss) || ++guard > GUARD_MAX) break;
      #pragma unroll
      for (int q = 0; q < 4; ++q)
        if ((unsigned)(v[q] >> 32) != (unsigned)SEQ)
          v[q] = __hip_atomic_load(&src[tid + TPB * q], __ATOMIC_RELAXED,
                                   __HIP_MEMORY_SCOPE_AGENT);
    }
    float sy = 0.f;
    #pragma unroll
    for (int q = 0; q < 4; ++q)
      sy = fmaf(wo[q], __uint_as_float((unsigned)v[q]), sy);
    #pragma unroll
    for (int off = 32; off >= 1; off >>= 1) sy += __shfl_xor(sy, off, 64);
    if (lane == 0) wys[0][wave] = sy;
    __syncthreads();
    if (tid == 0)
      out[SEQ - 1] = wys[0][0] + wys[0][1] + wys[0][2] + wys[0][3] +
                     wys[0][4] + wys[0][5] + wys[0][6] + wys[0][7] + bout;
  }
}

extern "C" void kernel_launch(void* const* d_in, const int* in_sizes, int n_in,
                              void* d_out, int out_size, void* d_ws, size_t ws_size,
                              hipStream_t stream) {
  const float* x     = (const float*)d_in[0];
  const float* w_ih  = (const float*)d_in[1];
  const float* w_hh  = (const float*)d_in[2];
  const float* b_ih  = (const float*)d_in[3];
  const float* b_hh  = (const float*)d_in[4];
  const float* w_out = (const float*)d_in[5];
  const float* b_out = (const float*)d_in[6];
  float* out = (float*)d_out;

  // ws layout: inbox[2][2048] u64 = 32 KB
  u64* inbox = (u64*)d_ws;

  lstm_init<<<16, 256, 0, stream>>>(inbox);
  lstm_persist<<<NWG, TPB, 0, stream>>>(x, w_ih, w_hh, b_ih, b_hh, w_out,
                                        b_out, out, inbox);
}